// Round 13
// baseline (303.414 us; speedup 1.0000x reference)
//
#include <hip/hip_runtime.h>
#include <stdint.h>
#include <math.h>

typedef unsigned short u16;
typedef uint32_t u32;
typedef short bf16x8 __attribute__((ext_vector_type(8)));   // 8 bf16 = 4 VGPRs
typedef float f32x4  __attribute__((ext_vector_type(4)));

#define DEV __device__ __forceinline__

DEV u16 f2bf(float f) {
    union { float f; u32 u; } x; x.f = f;
    u32 lsb = (x.u >> 16) & 1u;
    x.u += 0x7fffu + lsb;            // RNE
    return (u16)(x.u >> 16);
}

// pack two f32 -> two bf16 (round-half-up) in 3 VALU ops
DEV u32 pack2(float a, float b) {
    union { float f; u32 u; } x, y; x.f = a; y.f = b;
    return __builtin_amdgcn_perm(y.u + 0x8000u, x.u + 0x8000u, 0x07060302u);
}

#if __has_builtin(__builtin_amdgcn_exp2f)
DEV float fexp2(float x) { return __builtin_amdgcn_exp2f(x); }
#else
DEV float fexp2(float x) { return __expf(x * 0.69314718056f); }
#endif

DEV f32x4 mfma16(bf16x8 a, bf16x8 b, f32x4 c) {
    return __builtin_amdgcn_mfma_f32_16x16x32_bf16(a, b, c, 0, 0, 0);
}

// ---------------------------------------------------------------------------
// 0) prep: fused (a) transpose+convert x[b][c][s] f32 -> tok[b][s][c] bf16
//          (b) convert 4 f32 weight matrices -> bf16 dst[j][co][ci]
//          (c) zero the 256 attn pair-arrival flags (block 1024)
//    blocks 0..1023: transpose tiles; blocks 1024..2047: weight convert.
// ---------------------------------------------------------------------------
__global__ __launch_bounds__(256) void prep_kernel(const float* __restrict__ x,
                                                   u16* __restrict__ tok,
                                                   const float* __restrict__ w0,
                                                   const float* __restrict__ w1,
                                                   const float* __restrict__ w2,
                                                   const float* __restrict__ w3,
                                                   u16* __restrict__ dst,
                                                   u32* __restrict__ flags) {
    __shared__ u16 t[64][65];
    const int id = blockIdx.x, tid = threadIdx.x;
    if (id == 1024 && tid < 256) flags[tid] = 0;   // stream-ordered before attn
    if (id < 1024) {
        const int b = id >> 9, c0 = ((id >> 6) & 7) * 64, s0 = (id & 63) * 64;
        const float* xb = x + ((size_t)b * 512 + c0) * 4096 + s0;
        u16* tb = tok + ((size_t)b * 4096 + s0) * 512 + c0;
        {   // read: 64 rows (c) x 16 float4 cols (s)
            const int jc = tid & 15, i0 = tid >> 4;
#pragma unroll
            for (int ii = 0; ii < 4; ii++) {
                int i = i0 * 4 + ii;
                float4 v = *(const float4*)&xb[(size_t)i * 4096 + jc * 4];
                t[i][jc * 4 + 0] = f2bf(v.x);
                t[i][jc * 4 + 1] = f2bf(v.y);
                t[i][jc * 4 + 2] = f2bf(v.z);
                t[i][jc * 4 + 3] = f2bf(v.w);
            }
        }
        __syncthreads();
        {   // write: 64 rows (s) x 32 u32 cols (c pairs)
            const int j = tid & 31, i0 = tid >> 5;
#pragma unroll
            for (int ii = 0; ii < 8; ii++) {
                int srow = i0 * 8 + ii;
                u32 v = (u32)t[j * 2][srow] | ((u32)t[j * 2 + 1][srow] << 16);
                *(u32*)(&tb[(size_t)srow * 512 + j * 2]) = v;
            }
        }
    } else {
        const int id2 = id - 1024;
        const int j = id2 >> 8;
        const float* src = (j == 0) ? w0 : (j == 1) ? w1 : (j == 2) ? w2 : w3;
        int idx = ((id2 & 255) * 256 + tid) * 4;
        float4 v = *(const float4*)&src[idx];
        uint2 pv;
        pv.x = pack2(v.x, v.y);
        pv.y = pack2(v.z, v.w);
        *(uint2*)&dst[(size_t)j * 262144 + idx] = pv;
    }
}

// ---------------------------------------------------------------------------
// 1) FUSED QKV GEMM (R5, best verified): one kernel computes Q, K and V.
//    64co x 128s tile; tok B-tile staged ONCE per K-step and reused against
//    Wq/Wk/Wv A-tiles. Triple-buffered register staging, prefetch distance 2,
//    ONE barrier per step. LDS 60 KB. grid (32,8,2) = 512 blocks = 2/CU.
// ---------------------------------------------------------------------------
__global__ __launch_bounds__(256, 2) void qkv3_kernel(const u16* __restrict__ Wbf,
                                                      const float* __restrict__ bq,
                                                      const float* __restrict__ bk,
                                                      const float* __restrict__ bv,
                                                      const u16* __restrict__ tok,
                                                      u16* __restrict__ Qb,
                                                      u16* __restrict__ Kb,
                                                      u16* __restrict__ Vb) {
    __shared__ u16 Alds[3][6144];    // 3 bufs x (3 j x 4KB) = 36KB
    __shared__ u16 Blds[3][4096];    // 3 bufs x 8KB = 24KB
    const int tid = threadIdx.x;
    const int wave = tid >> 6, lane = tid & 63, q = lane >> 4, c = lane & 15;
    const int n0 = blockIdx.x * 128;     // s
    const int m0 = blockIdx.y * 64;      // co
    const int b  = blockIdx.z;
    const u16* tokb = tok + (size_t)b * (4096 * 512);

    const int cs = tid & 15, qs = (tid >> 4) & 3, ms = tid >> 6;
    const u16* As0 = Wbf +          (size_t)(m0 + ms * 16 + cs) * 512 + qs * 8;
    const u16* As1 = Wbf + 262144 + (size_t)(m0 + ms * 16 + cs) * 512 + qs * 8;
    const u16* As2 = Wbf + 524288 + (size_t)(m0 + ms * 16 + cs) * 512 + qs * 8;
    const u16* Bsrc0 = tokb + (size_t)(n0 + ms * 16 + cs) * 512 + qs * 8;
    const u16* Bsrc1 = tokb + (size_t)(n0 + (ms + 4) * 16 + cs) * 512 + qs * 8;

    f32x4 acc[3][2][4] = {};

    // prologue: chunk 0 -> LDS buf 0; chunk 1 held in registers
    int4 pA0 = *(const int4*)&As0[0];
    int4 pA1 = *(const int4*)&As1[0];
    int4 pA2 = *(const int4*)&As2[0];
    int4 pB0 = *(const int4*)&Bsrc0[0];
    int4 pB1 = *(const int4*)&Bsrc1[0];
    int4 hA0 = *(const int4*)&As0[32];
    int4 hA1 = *(const int4*)&As1[32];
    int4 hA2 = *(const int4*)&As2[32];
    int4 hB0 = *(const int4*)&Bsrc0[32];
    int4 hB1 = *(const int4*)&Bsrc1[32];
    *(int4*)&Alds[0][tid * 8]        = pA0;
    *(int4*)&Alds[0][2048 + tid * 8] = pA1;
    *(int4*)&Alds[0][4096 + tid * 8] = pA2;
    *(int4*)&Blds[0][tid * 8]         = pB0;
    *(int4*)&Blds[0][(tid + 256) * 8] = pB1;
    __syncthreads();

    int p = 0, pw = 1;
    for (int it = 0; it < 16; it++) {
        const int kn = ((it + 2) & 15) * 32;   // chunk to prefetch (wraps; harmless)

        // (1) issue loads for chunk it+2
        int4 nA0 = *(const int4*)&As0[kn];
        int4 nA1 = *(const int4*)&As1[kn];
        int4 nA2 = *(const int4*)&As2[kn];
        int4 nB0 = *(const int4*)&Bsrc0[kn];
        int4 nB1 = *(const int4*)&Bsrc1[kn];

        // (2) compute on buffer p (holds chunk it)
        bf16x8 bfr[4];
#pragma unroll
        for (int t = 0; t < 4; t++) {
            int gn = (((wave >> 1) * 4 + t) * 4 + q) * 16 + c;
            bfr[t] = *(const bf16x8*)&Blds[p][gn * 8];
        }
#pragma unroll
        for (int j = 0; j < 3; j++) {
            bf16x8 af[2];
#pragma unroll
            for (int mt = 0; mt < 2; mt++) {
                int gm = ((((wave & 1) * 2 + mt) * 4 + q) * 16 + c);
                af[mt] = *(const bf16x8*)&Alds[p][j * 2048 + gm * 8];
            }
#pragma unroll
            for (int mt = 0; mt < 2; mt++)
#pragma unroll
                for (int nt = 0; nt < 4; nt++)
                    acc[j][mt][nt] = mfma16(af[mt], bfr[nt], acc[j][mt][nt]);
        }

        // (3) write held chunk it+1 into buffer pw
        *(int4*)&Alds[pw][tid * 8]        = hA0;
        *(int4*)&Alds[pw][2048 + tid * 8] = hA1;
        *(int4*)&Alds[pw][4096 + tid * 8] = hA2;
        *(int4*)&Blds[pw][tid * 8]         = hB0;
        *(int4*)&Blds[pw][(tid + 256) * 8] = hB1;
        hA0 = nA0; hA1 = nA1; hA2 = nA2; hB0 = nB0; hB1 = nB1;
        __syncthreads();
        p = pw; pw = (pw == 2) ? 0 : pw + 1;
    }

    // epilogue: co = mbase+mt*16+q*4+reg ; s = nbase+nt*16+c
    const int mbase = m0 + (wave & 1) * 32, nbase = n0 + (wave >> 1) * 64;
    const int hd = m0 >> 6;
#pragma unroll
    for (int j = 0; j < 3; j++) {
        const float* bias = (j == 0) ? bq : (j == 1) ? bk : bv;
        const float scale = (j == 0) ? 0.1803368801f : 1.0f;   // log2(e)/8
        u16* outm = (j == 0) ? Qb : Kb;
#pragma unroll
        for (int mt = 0; mt < 2; mt++) {
            int co0 = mbase + mt * 16 + q * 4;
            float b0 = bias[co0 + 0], b1 = bias[co0 + 1];
            float b2 = bias[co0 + 2], b3 = bias[co0 + 3];
#pragma unroll
            for (int nt = 0; nt < 4; nt++) {
                int scol = nbase + nt * 16 + c;
                float v0 = (acc[j][mt][nt][0] + b0) * scale;
                float v1 = (acc[j][mt][nt][1] + b1) * scale;
                float v2 = (acc[j][mt][nt][2] + b2) * scale;
                float v3 = (acc[j][mt][nt][3] + b3) * scale;
                if (j < 2) {
                    uint2 pv; pv.x = pack2(v0, v1); pv.y = pack2(v2, v3);
                    size_t idx = ((size_t)(b * 8 + hd) * 4096 + scol) * 64 + (co0 & 63);
                    *(uint2*)&outm[idx] = pv;
                } else {
                    Vb[((size_t)(b * 512 + co0 + 0)) * 4096 + scol] = f2bf(v0);
                    Vb[((size_t)(b * 512 + co0 + 1)) * 4096 + scol] = f2bf(v1);
                    Vb[((size_t)(b * 512 + co0 + 2)) * 4096 + scol] = f2bf(v2);
                    Vb[((size_t)(b * 512 + co0 + 3)) * 4096 + scol] = f2bf(v3);
                }
            }
        }
    }
}

// ---------------------------------------------------------------------------
// 2) Projection GEMM core (R3/R5/R8, CONTROL): TRIPLE-BUFFERED, prefetch
//    distance 2, 128x128 tile, BK=32, 16 K-steps, ONE barrier per step.
//    LDS 48 KB. out f32 [b*512+co][s].
// ---------------------------------------------------------------------------
DEV void proj_core(const u16* __restrict__ W, const float* __restrict__ bias,
                   const u16* __restrict__ Bb, void* __restrict__ out,
                   int b, int mode, float scale,
                   u16 (*__restrict__ Alds)[4096], u16 (*__restrict__ Blds)[4096]) {
    const int tid = threadIdx.x;
    const int wave = tid >> 6, lane = tid & 63, q = lane >> 4, c = lane & 15;
    const int m0 = blockIdx.y * 128, n0 = blockIdx.x * 128;

    const int cs = tid & 15, qs = (tid >> 4) & 3, ms = (tid >> 6) & 3;
    const u16* Asrc0 = W  + (size_t)(m0 + ms * 16 + cs) * 512 + qs * 8;
    const u16* Asrc1 = W  + (size_t)(m0 + (ms + 4) * 16 + cs) * 512 + qs * 8;
    const u16* Bsrc0 = Bb + (size_t)(n0 + ms * 16 + cs) * 512 + qs * 8;
    const u16* Bsrc1 = Bb + (size_t)(n0 + (ms + 4) * 16 + cs) * 512 + qs * 8;

    f32x4 acc[4][4] = {};

    int4 pa0 = *(const int4*)&Asrc0[0];
    int4 pa1 = *(const int4*)&Asrc1[0];
    int4 pb0 = *(const int4*)&Bsrc0[0];
    int4 pb1 = *(const int4*)&Bsrc1[0];
    int4 ha0 = *(const int4*)&Asrc0[32];
    int4 ha1 = *(const int4*)&Asrc1[32];
    int4 hb0 = *(const int4*)&Bsrc0[32];
    int4 hb1 = *(const int4*)&Bsrc1[32];
    *(int4*)&Alds[0][tid * 8]         = pa0;
    *(int4*)&Alds[0][(tid + 256) * 8] = pa1;
    *(int4*)&Blds[0][tid * 8]         = pb0;
    *(int4*)&Blds[0][(tid + 256) * 8] = pb1;
    __syncthreads();

    int p = 0, pw = 1;
    for (int it = 0; it < 16; it++) {
        const int kn = ((it + 2) & 15) * 32;

        int4 na0 = *(const int4*)&Asrc0[kn];
        int4 na1 = *(const int4*)&Asrc1[kn];
        int4 nb0 = *(const int4*)&Bsrc0[kn];
        int4 nb1 = *(const int4*)&Bsrc1[kn];

        bf16x8 af[4], bfr[4];
#pragma unroll
        for (int t = 0; t < 4; t++) {
            int gm = (((wave & 1) * 4 + t) * 4 + q) * 16 + c;
            af[t] = *(const bf16x8*)&Alds[p][gm * 8];
            int gn = (((wave >> 1) * 4 + t) * 4 + q) * 16 + c;
            bfr[t] = *(const bf16x8*)&Blds[p][gn * 8];
        }
#pragma unroll
        for (int mt = 0; mt < 4; mt++)
#pragma unroll
            for (int nt = 0; nt < 4; nt++)
                acc[mt][nt] = mfma16(af[mt], bfr[nt], acc[mt][nt]);

        *(int4*)&Alds[pw][tid * 8]         = ha0;
        *(int4*)&Alds[pw][(tid + 256) * 8] = ha1;
        *(int4*)&Blds[pw][tid * 8]         = hb0;
        *(int4*)&Blds[pw][(tid + 256) * 8] = hb1;
        ha0 = na0; ha1 = na1; hb0 = nb0; hb1 = nb1;
        __syncthreads();
        p = pw; pw = (pw == 2) ? 0 : pw + 1;
    }

    const int mbase = m0 + (wave & 1) * 64, nbase = n0 + (wave >> 1) * 64;
#pragma unroll
    for (int mt = 0; mt < 4; mt++) {
        int co0 = mbase + mt * 16 + q * 4;
        float b0 = bias[co0 + 0], b1 = bias[co0 + 1];
        float b2 = bias[co0 + 2], b3 = bias[co0 + 3];
#pragma unroll
        for (int nt = 0; nt < 4; nt++) {
            int scol = nbase + nt * 16 + c;
            float v0 = (acc[mt][nt][0] + b0) * scale;
            float v1 = (acc[mt][nt][1] + b1) * scale;
            float v2 = (acc[mt][nt][2] + b2) * scale;
            float v3 = (acc[mt][nt][3] + b3) * scale;
            float* o = (float*)out;
            o[((size_t)(b * 512 + co0 + 0)) * 4096 + scol] = v0;
            o[((size_t)(b * 512 + co0 + 1)) * 4096 + scol] = v1;
            o[((size_t)(b * 512 + co0 + 2)) * 4096 + scol] = v2;
            o[((size_t)(b * 512 + co0 + 3)) * 4096 + scol] = v3;
        }
    }
    (void)mode;
}

// final projection: blockIdx.z = batch, f32 output (CONTROL)
__global__ __launch_bounds__(256) void projp_kernel(const u16* __restrict__ Wp,
                                                    const float* __restrict__ bp,
                                                    const u16* __restrict__ attout,
                                                    float* __restrict__ out) {
    __shared__ u16 Alds[3][4096];
    __shared__ u16 Blds[3][4096];
    const int b = blockIdx.z;
    proj_core(Wp, bp, attout + (size_t)b * (4096 * 512), out, b, 2, 1.0f, Alds, Blds);
}

// ---------------------------------------------------------------------------
// 3) Flash attention (R12 structure + R13 FUSED MERGE): 8-wave blocks,
//    s-tile 256, grid (16,16,2) = 512 blocks = 2/CU x 8 waves. Main loop
//    byte-identical to R12 (best measured: 96.8 us). Epilogue: both z-blocks
//    of a (s-tile,bhd) pair write unnormalized partials; the SECOND arriver
//    (device-scope atomic flag; release = syncthreads-drain + threadfence +
//    atomicAdd, acquire = threadfence after atomic, per G12/G16) merges:
//    own partial from REGISTERS + other half from HBM/L2, normalize, write
//    attout. Replaces the separate merge kernel (42MB serial + 2 boundaries)
//    with ~25MB overlapped in attn's tail.
// ---------------------------------------------------------------------------
__global__ __launch_bounds__(512, 4) void attn_kernel(const u16* __restrict__ Qm,
                                                      const u16* __restrict__ Km,
                                                      const u16* __restrict__ Vm,
                                                      float* __restrict__ Opart,
                                                      float* __restrict__ Lpart,
                                                      u32* __restrict__ flags,
                                                      u16* __restrict__ attout) {
    __shared__ u16 Klds[2][4096];     // 2 x 8KB, frag order (t4,kk,qq,r)
    __shared__ u16 Vlds[2][4096];     // 2 x 8KB, frag order (t4,kk,qq,r)
    __shared__ u16 Plds[8][512];      // per-wave 1KB frag-order P^T (one st,kt)
    __shared__ u32 whoflag;
    const int tid = threadIdx.x, wave = tid >> 6, lane = tid & 63;
    const int q = lane >> 4, c = lane & 15;
    const int bhd = blockIdx.y, s0 = blockIdx.x * 256, z = blockIdx.z;
    const int tbase = z * 2048;
    const u16* Qb = Qm + (size_t)bhd * (4096 * 64);
    const u16* Kb = Km + (size_t)bhd * (4096 * 64);
    const u16* Vb = Vm + (size_t)bhd * (64 * 4096);

    // Q B-frags for this wave's 32 s-rows (Q pre-scaled by log2e/8)
    bf16x8 qf[2][2];
#pragma unroll
    for (int st = 0; st < 2; st++)
#pragma unroll
        for (int kd = 0; kd < 2; kd++)
            qf[st][kd] = *(const bf16x8*)
                &Qb[(size_t)(s0 + wave * 32 + st * 16 + c) * 64 + kd * 32 + q * 8];

    // staging: 512 threads stage 512 granules (one K + one V each).
    const int rr = tid & 15, qq = (tid >> 4) & 3, kk = (tid >> 6) & 1;
    const int t4 = tid >> 7;   // 0..3
    const u16* Ksrc = Kb + (size_t)(tbase + t4 * 16 + rr) * 64 + kk * 32 + qq * 8;
    const u16* Vsrc = Vb + (size_t)(t4 * 16 + rr) * 4096 + tbase + kk * 32 + qq * 8;

    // per-lane P bases (u16 index into this wave's 512-u16 region)
    u16* Pwr       = &Plds[wave][(q >> 1) * 128 + (q & 1) * 4 + c * 8];
    const u16* Prd = &Plds[wave][q * 128 + c * 8];

    f32x4 oacc[4][2] = {};            // [dt][st]: O^T rows dv, cols s
    float lsum[2] = {0.f, 0.f};

    *(int4*)&Klds[0][tid * 8] = *(const int4*)&Ksrc[0];
    *(int4*)&Vlds[0][tid * 8] = *(const int4*)&Vsrc[0];
    __syncthreads();

    for (int it = 0; it < 32; it++) {
        const int p = it & 1;
        const size_t t0n = (size_t)(((it + 1) & 31) * 64);  // next tile (wraps)

        // (1) issue next-tile global loads into VGPRs (land under compute)
        int4 kst = *(const int4*)&Ksrc[t0n * 64];
        int4 vst = *(const int4*)&Vsrc[t0n];

        // (2) QK^T on K tile it (both st halves)
        f32x4 sacc[4][2] = {};
#pragma unroll
        for (int kd = 0; kd < 2; kd++) {
            bf16x8 ka[4];
#pragma unroll
            for (int tt = 0; tt < 4; tt++)
                ka[tt] = *(const bf16x8*)&Klds[p][(((tt * 2 + kd) * 4 + q) * 16 + c) * 8];
#pragma unroll
            for (int tt = 0; tt < 4; tt++)
#pragma unroll
                for (int st = 0; st < 2; st++)
                    sacc[tt][st] = mfma16(ka[tt], qf[st][kd], sacc[tt][st]);
        }

        // (2b) hoist V frags to registers ONCE per iter
        bf16x8 va[2][4];
#pragma unroll
        for (int kt = 0; kt < 2; kt++)
#pragma unroll
            for (int dt = 0; dt < 4; dt++)
                va[kt][dt] = *(const bf16x8*)&Vlds[p][(((dt * 2 + kt) * 4 + q) * 16 + c) * 8];

        // (3) per (st,kt): softmax quadrant -> P (1KB/wave, reused 4x), PV.
#pragma unroll
        for (int st = 0; st < 2; st++) {
#pragma unroll
            for (int kt = 0; kt < 2; kt++) {
#pragma unroll
                for (int t2 = 0; t2 < 2; t2++) {
                    const int tt = kt * 2 + t2;
                    float p0 = fexp2(sacc[tt][st][0]);
                    float p1 = fexp2(sacc[tt][st][1]);
                    float p2 = fexp2(sacc[tt][st][2]);
                    float p3 = fexp2(sacc[tt][st][3]);
                    lsum[st] += (p0 + p1) + (p2 + p3);
                    uint2 pv; pv.x = pack2(p0, p1); pv.y = pack2(p2, p3);
                    *(uint2*)&Pwr[t2 * 256] = pv;
                }
                bf16x8 pb = *(const bf16x8*)&Prd[0];
#pragma unroll
                for (int dt = 0; dt < 4; dt++)
                    oacc[dt][st] = mfma16(va[kt][dt], pb, oacc[dt][st]);
            }
        }

        // (4) write staged regs into the other buffer; (5) single barrier
        *(int4*)&Klds[1 - p][tid * 8] = kst;
        *(int4*)&Vlds[1 - p][tid * 8] = vst;
        __syncthreads();
    }

    // epilogue A: write unnormalized partials (always)
    float lown[2];
#pragma unroll
    for (int st = 0; st < 2; st++) {
        float l = lsum[st];
        l += __shfl_xor(l, 16, 64);
        l += __shfl_xor(l, 32, 64);
        lown[st] = l;
        const int s = s0 + wave * 32 + st * 16 + c;
        const size_t rowbase = ((size_t)(z * 16 + bhd) * 4096 + s) * 64;
#pragma unroll
        for (int dt = 0; dt < 4; dt++) {
            float4 ov;
            ov.x = oacc[dt][st][0];
            ov.y = oacc[dt][st][1];
            ov.z = oacc[dt][st][2];
            ov.w = oacc[dt][st][3];
            *(float4*)&Opart[rowbase + dt * 16 + q * 4] = ov;
        }
        if (lane < 16)
            Lpart[(size_t)z * 65536 + bhd * 4096 + s0 + wave * 32 + st * 16 + lane] = l;
    }

    // epilogue B: pair arrival protocol. __syncthreads drains every wave's
    // stores (vmcnt(0) before s_barrier); threadfence makes them device-
    // visible (L2 writeback); atomicAdd is the release point.
    __syncthreads();
    if (tid == 0) {
        __threadfence();
        whoflag = atomicAdd(&flags[bhd * 16 + blockIdx.x], 1u);
    }
    __syncthreads();

    // epilogue C: second arriver merges (own regs + other half from memory)
    if (whoflag == 1) {
        __threadfence();   // acquire: invalidate stale L1/L2 before reads
        const int zo = 1 - z;
        const int b = bhd >> 3, hd = bhd & 7;
#pragma unroll
        for (int st = 0; st < 2; st++) {
            const int s = s0 + wave * 32 + st * 16 + c;
            const float lo = Lpart[(size_t)zo * 65536 + bhd * 4096 + s];
            const float rl = 1.0f / (lown[st] + lo);
            const size_t rowo = ((size_t)(zo * 16 + bhd) * 4096 + s) * 64;
#pragma unroll
            for (int dt = 0; dt < 4; dt++) {
                float4 o4 = *(const float4*)&Opart[rowo + dt * 16 + q * 4];
                uint2 pv;
                pv.x = pack2((oacc[dt][st][0] + o4.x) * rl,
                             (oacc[dt][st][1] + o4.y) * rl);
                pv.y = pack2((oacc[dt][st][2] + o4.z) * rl,
                             (oacc[dt][st][3] + o4.w) * rl);
                *(uint2*)&attout[((size_t)(b * 4096 + s)) * 512 + hd * 64 + dt * 16 + q * 4] = pv;
            }
        }
    }
}

// ---------------------------------------------------------------------------
extern "C" void kernel_launch(void* const* d_in, const int* in_sizes, int n_in,
                              void* d_out, int out_size, void* d_ws, size_t ws_size,
                              hipStream_t stream) {
    (void)in_sizes; (void)n_in; (void)out_size; (void)ws_size;
    const float* x  = (const float*)d_in[0];
    const float* Wq = (const float*)d_in[1];
    const float* bq = (const float*)d_in[2];
    const float* Wk = (const float*)d_in[3];
    const float* bk = (const float*)d_in[4];
    const float* Wv = (const float*)d_in[5];
    const float* bv = (const float*)d_in[6];
    const float* Wp = (const float*)d_in[7];
    const float* bp = (const float*)d_in[8];
    float* out = (float*)d_out;

    const size_t NTOK = (size_t)4 * 1024 * 1024;  // 2*4096*512 elements
    u16* tok = (u16*)d_ws;        // [2][4096][512] bf16; reused as attout later
    u16* Qb  = tok + NTOK;        // [16][4096][64]  (pre-scaled by log2e/8)
    u16* Kb  = Qb + NTOK;         // [16][4096][64]
    u16* Vb  = Kb + NTOK;         // [16][64][4096]
    u16* Wbf = Vb + NTOK;         // [4][512][512] bf16 (q,k,v,p)
    u16* attout = tok;            // alias: tok dead after V projection
    float* Opart = (float*)(Wbf + 4 * 262144);  // [2][16][4096][64] f32 (33.5MB)
    float* Lpart = Opart + (size_t)2 * 4194304; // [2][16][4096] f32 (512KB)
    u32* flags   = (u32*)(Lpart + (size_t)2 * 65536);  // 256 pair flags (1KB)

    prep_kernel<<<dim3(2048), 256, 0, stream>>>(x, tok, Wq, Wk, Wv, Wp, Wbf, flags);
    qkv3_kernel<<<dim3(32, 8, 2), 256, 0, stream>>>(Wbf, bq, bk, bv, tok, Qb, Kb, Vb);
    attn_kernel<<<dim3(16, 16, 2), 512, 0, stream>>>(Qb, Kb, Vb, Opart, Lpart, flags, attout);
    projp_kernel<<<dim3(32, 4, 2), 256, 0, stream>>>(Wbf + 3 * 262144, bp, attout, out);
}

// Round 14
// 215.915 us; speedup vs baseline: 1.4053x; 1.4053x over previous
//
#include <hip/hip_runtime.h>
#include <stdint.h>
#include <math.h>

typedef unsigned short u16;
typedef uint32_t u32;
typedef short bf16x8 __attribute__((ext_vector_type(8)));   // 8 bf16 = 4 VGPRs
typedef float f32x4  __attribute__((ext_vector_type(4)));

#define DEV __device__ __forceinline__

DEV u16 f2bf(float f) {
    union { float f; u32 u; } x; x.f = f;
    u32 lsb = (x.u >> 16) & 1u;
    x.u += 0x7fffu + lsb;            // RNE
    return (u16)(x.u >> 16);
}

// pack two f32 -> two bf16 (round-half-up) in 3 VALU ops
DEV u32 pack2(float a, float b) {
    union { float f; u32 u; } x, y; x.f = a; y.f = b;
    return __builtin_amdgcn_perm(y.u + 0x8000u, x.u + 0x8000u, 0x07060302u);
}

#if __has_builtin(__builtin_amdgcn_exp2f)
DEV float fexp2(float x) { return __builtin_amdgcn_exp2f(x); }
#else
DEV float fexp2(float x) { return __expf(x * 0.69314718056f); }
#endif

DEV f32x4 mfma16(bf16x8 a, bf16x8 b, f32x4 c) {
    return __builtin_amdgcn_mfma_f32_16x16x32_bf16(a, b, c, 0, 0, 0);
}

// ---------------------------------------------------------------------------
// 0) prep: fused (a) transpose+convert x[b][c][s] f32 -> tok[b][s][c] bf16
//          (b) convert 4 f32 weight matrices -> bf16 dst[j][co][ci]
//    blocks 0..1023: transpose tiles; blocks 1024..2047: weight convert.
// ---------------------------------------------------------------------------
__global__ __launch_bounds__(256) void prep_kernel(const float* __restrict__ x,
                                                   u16* __restrict__ tok,
                                                   const float* __restrict__ w0,
                                                   const float* __restrict__ w1,
                                                   const float* __restrict__ w2,
                                                   const float* __restrict__ w3,
                                                   u16* __restrict__ dst) {
    __shared__ u16 t[64][65];
    const int id = blockIdx.x, tid = threadIdx.x;
    if (id < 1024) {
        const int b = id >> 9, c0 = ((id >> 6) & 7) * 64, s0 = (id & 63) * 64;
        const float* xb = x + ((size_t)b * 512 + c0) * 4096 + s0;
        u16* tb = tok + ((size_t)b * 4096 + s0) * 512 + c0;
        {   // read: 64 rows (c) x 16 float4 cols (s)
            const int jc = tid & 15, i0 = tid >> 4;
#pragma unroll
            for (int ii = 0; ii < 4; ii++) {
                int i = i0 * 4 + ii;
                float4 v = *(const float4*)&xb[(size_t)i * 4096 + jc * 4];
                t[i][jc * 4 + 0] = f2bf(v.x);
                t[i][jc * 4 + 1] = f2bf(v.y);
                t[i][jc * 4 + 2] = f2bf(v.z);
                t[i][jc * 4 + 3] = f2bf(v.w);
            }
        }
        __syncthreads();
        {   // write: 64 rows (s) x 32 u32 cols (c pairs)
            const int j = tid & 31, i0 = tid >> 5;
#pragma unroll
            for (int ii = 0; ii < 8; ii++) {
                int srow = i0 * 8 + ii;
                u32 v = (u32)t[j * 2][srow] | ((u32)t[j * 2 + 1][srow] << 16);
                *(u32*)(&tb[(size_t)srow * 512 + j * 2]) = v;
            }
        }
    } else {
        const int id2 = id - 1024;
        const int j = id2 >> 8;
        const float* src = (j == 0) ? w0 : (j == 1) ? w1 : (j == 2) ? w2 : w3;
        int idx = ((id2 & 255) * 256 + tid) * 4;
        float4 v = *(const float4*)&src[idx];
        uint2 pv;
        pv.x = pack2(v.x, v.y);
        pv.y = pack2(v.z, v.w);
        *(uint2*)&dst[(size_t)j * 262144 + idx] = pv;
    }
}

// ---------------------------------------------------------------------------
// 1) FUSED QKV GEMM (R5, validated): one kernel computes Q, K and V. Each
//    block owns a 64(co) x 128(s) output tile and stages the tok B-tile ONCE
//    per K-step, reusing it against Wq/Wk/Wv A-tiles. Triple-buffered
//    register staging, prefetch distance 2, ONE barrier per step. LDS 60 KB.
//    grid (32 s, 8 co, 2 b) = 512 blocks = 2/CU.
// ---------------------------------------------------------------------------
__global__ __launch_bounds__(256, 2) void qkv3_kernel(const u16* __restrict__ Wbf,
                                                      const float* __restrict__ bq,
                                                      const float* __restrict__ bk,
                                                      const float* __restrict__ bv,
                                                      const u16* __restrict__ tok,
                                                      u16* __restrict__ Qb,
                                                      u16* __restrict__ Kb,
                                                      u16* __restrict__ Vb) {
    __shared__ u16 Alds[3][6144];    // 3 bufs x (3 j x 4KB) = 36KB
    __shared__ u16 Blds[3][4096];    // 3 bufs x 8KB = 24KB
    const int tid = threadIdx.x;
    const int wave = tid >> 6, lane = tid & 63, q = lane >> 4, c = lane & 15;
    const int n0 = blockIdx.x * 128;     // s
    const int m0 = blockIdx.y * 64;      // co
    const int b  = blockIdx.z;
    const u16* tokb = tok + (size_t)b * (4096 * 512);

    const int cs = tid & 15, qs = (tid >> 4) & 3, ms = tid >> 6;
    const u16* As0 = Wbf +          (size_t)(m0 + ms * 16 + cs) * 512 + qs * 8;
    const u16* As1 = Wbf + 262144 + (size_t)(m0 + ms * 16 + cs) * 512 + qs * 8;
    const u16* As2 = Wbf + 524288 + (size_t)(m0 + ms * 16 + cs) * 512 + qs * 8;
    const u16* Bsrc0 = tokb + (size_t)(n0 + ms * 16 + cs) * 512 + qs * 8;
    const u16* Bsrc1 = tokb + (size_t)(n0 + (ms + 4) * 16 + cs) * 512 + qs * 8;

    f32x4 acc[3][2][4] = {};

    // prologue: chunk 0 -> LDS buf 0; chunk 1 held in registers
    int4 pA0 = *(const int4*)&As0[0];
    int4 pA1 = *(const int4*)&As1[0];
    int4 pA2 = *(const int4*)&As2[0];
    int4 pB0 = *(const int4*)&Bsrc0[0];
    int4 pB1 = *(const int4*)&Bsrc1[0];
    int4 hA0 = *(const int4*)&As0[32];
    int4 hA1 = *(const int4*)&As1[32];
    int4 hA2 = *(const int4*)&As2[32];
    int4 hB0 = *(const int4*)&Bsrc0[32];
    int4 hB1 = *(const int4*)&Bsrc1[32];
    *(int4*)&Alds[0][tid * 8]        = pA0;
    *(int4*)&Alds[0][2048 + tid * 8] = pA1;
    *(int4*)&Alds[0][4096 + tid * 8] = pA2;
    *(int4*)&Blds[0][tid * 8]         = pB0;
    *(int4*)&Blds[0][(tid + 256) * 8] = pB1;
    __syncthreads();

    int p = 0, pw = 1;
    for (int it = 0; it < 16; it++) {
        const int kn = ((it + 2) & 15) * 32;   // chunk to prefetch (wraps; harmless)

        // (1) issue loads for chunk it+2
        int4 nA0 = *(const int4*)&As0[kn];
        int4 nA1 = *(const int4*)&As1[kn];
        int4 nA2 = *(const int4*)&As2[kn];
        int4 nB0 = *(const int4*)&Bsrc0[kn];
        int4 nB1 = *(const int4*)&Bsrc1[kn];

        // (2) compute on buffer p (holds chunk it)
        bf16x8 bfr[4];
#pragma unroll
        for (int t = 0; t < 4; t++) {
            int gn = (((wave >> 1) * 4 + t) * 4 + q) * 16 + c;
            bfr[t] = *(const bf16x8*)&Blds[p][gn * 8];
        }
#pragma unroll
        for (int j = 0; j < 3; j++) {
            bf16x8 af[2];
#pragma unroll
            for (int mt = 0; mt < 2; mt++) {
                int gm = ((((wave & 1) * 2 + mt) * 4 + q) * 16 + c);
                af[mt] = *(const bf16x8*)&Alds[p][j * 2048 + gm * 8];
            }
#pragma unroll
            for (int mt = 0; mt < 2; mt++)
#pragma unroll
                for (int nt = 0; nt < 4; nt++)
                    acc[j][mt][nt] = mfma16(af[mt], bfr[nt], acc[j][mt][nt]);
        }

        // (3) write held chunk it+1 into buffer pw
        *(int4*)&Alds[pw][tid * 8]        = hA0;
        *(int4*)&Alds[pw][2048 + tid * 8] = hA1;
        *(int4*)&Alds[pw][4096 + tid * 8] = hA2;
        *(int4*)&Blds[pw][tid * 8]         = hB0;
        *(int4*)&Blds[pw][(tid + 256) * 8] = hB1;
        hA0 = nA0; hA1 = nA1; hA2 = nA2; hB0 = nB0; hB1 = nB1;
        __syncthreads();
        p = pw; pw = (pw == 2) ? 0 : pw + 1;
    }

    // epilogue: co = mbase+mt*16+q*4+reg ; s = nbase+nt*16+c
    const int mbase = m0 + (wave & 1) * 32, nbase = n0 + (wave >> 1) * 64;
    const int hd = m0 >> 6;
#pragma unroll
    for (int j = 0; j < 3; j++) {
        const float* bias = (j == 0) ? bq : (j == 1) ? bk : bv;
        const float scale = (j == 0) ? 0.1803368801f : 1.0f;   // log2(e)/8
        u16* outm = (j == 0) ? Qb : Kb;
#pragma unroll
        for (int mt = 0; mt < 2; mt++) {
            int co0 = mbase + mt * 16 + q * 4;
            float b0 = bias[co0 + 0], b1 = bias[co0 + 1];
            float b2 = bias[co0 + 2], b3 = bias[co0 + 3];
#pragma unroll
            for (int nt = 0; nt < 4; nt++) {
                int scol = nbase + nt * 16 + c;
                float v0 = (acc[j][mt][nt][0] + b0) * scale;
                float v1 = (acc[j][mt][nt][1] + b1) * scale;
                float v2 = (acc[j][mt][nt][2] + b2) * scale;
                float v3 = (acc[j][mt][nt][3] + b3) * scale;
                if (j < 2) {
                    uint2 pv; pv.x = pack2(v0, v1); pv.y = pack2(v2, v3);
                    size_t idx = ((size_t)(b * 8 + hd) * 4096 + scol) * 64 + (co0 & 63);
                    *(uint2*)&outm[idx] = pv;
                } else {
                    Vb[((size_t)(b * 512 + co0 + 0)) * 4096 + scol] = f2bf(v0);
                    Vb[((size_t)(b * 512 + co0 + 1)) * 4096 + scol] = f2bf(v1);
                    Vb[((size_t)(b * 512 + co0 + 2)) * 4096 + scol] = f2bf(v2);
                    Vb[((size_t)(b * 512 + co0 + 3)) * 4096 + scol] = f2bf(v3);
                }
            }
        }
    }
}

// ---------------------------------------------------------------------------
// 2) Projection GEMM core (R3/R5 structure): TRIPLE-BUFFERED, prefetch
//    distance 2, 128x128 tile, BK=32, 16 K-steps, ONE barrier per step.
//    LDS 48 KB. out f32 [b*512+co][s].
// ---------------------------------------------------------------------------
DEV void proj_core(const u16* __restrict__ W, const float* __restrict__ bias,
                   const u16* __restrict__ Bb, void* __restrict__ out,
                   int b, int mode, float scale,
                   u16 (*__restrict__ Alds)[4096], u16 (*__restrict__ Blds)[4096]) {
    const int tid = threadIdx.x;
    const int wave = tid >> 6, lane = tid & 63, q = lane >> 4, c = lane & 15;
    const int m0 = blockIdx.y * 128, n0 = blockIdx.x * 128;

    const int cs = tid & 15, qs = (tid >> 4) & 3, ms = (tid >> 6) & 3;
    const u16* Asrc0 = W  + (size_t)(m0 + ms * 16 + cs) * 512 + qs * 8;
    const u16* Asrc1 = W  + (size_t)(m0 + (ms + 4) * 16 + cs) * 512 + qs * 8;
    const u16* Bsrc0 = Bb + (size_t)(n0 + ms * 16 + cs) * 512 + qs * 8;
    const u16* Bsrc1 = Bb + (size_t)(n0 + (ms + 4) * 16 + cs) * 512 + qs * 8;

    f32x4 acc[4][4] = {};

    int4 pa0 = *(const int4*)&Asrc0[0];
    int4 pa1 = *(const int4*)&Asrc1[0];
    int4 pb0 = *(const int4*)&Bsrc0[0];
    int4 pb1 = *(const int4*)&Bsrc1[0];
    int4 ha0 = *(const int4*)&Asrc0[32];
    int4 ha1 = *(const int4*)&Asrc1[32];
    int4 hb0 = *(const int4*)&Bsrc0[32];
    int4 hb1 = *(const int4*)&Bsrc1[32];
    *(int4*)&Alds[0][tid * 8]         = pa0;
    *(int4*)&Alds[0][(tid + 256) * 8] = pa1;
    *(int4*)&Blds[0][tid * 8]         = pb0;
    *(int4*)&Blds[0][(tid + 256) * 8] = pb1;
    __syncthreads();

    int p = 0, pw = 1;
    for (int it = 0; it < 16; it++) {
        const int kn = ((it + 2) & 15) * 32;

        int4 na0 = *(const int4*)&Asrc0[kn];
        int4 na1 = *(const int4*)&Asrc1[kn];
        int4 nb0 = *(const int4*)&Bsrc0[kn];
        int4 nb1 = *(const int4*)&Bsrc1[kn];

        bf16x8 af[4], bfr[4];
#pragma unroll
        for (int t = 0; t < 4; t++) {
            int gm = (((wave & 1) * 4 + t) * 4 + q) * 16 + c;
            af[t] = *(const bf16x8*)&Alds[p][gm * 8];
            int gn = (((wave >> 1) * 4 + t) * 4 + q) * 16 + c;
            bfr[t] = *(const bf16x8*)&Blds[p][gn * 8];
        }
#pragma unroll
        for (int mt = 0; mt < 4; mt++)
#pragma unroll
            for (int nt = 0; nt < 4; nt++)
                acc[mt][nt] = mfma16(af[mt], bfr[nt], acc[mt][nt]);

        *(int4*)&Alds[pw][tid * 8]         = ha0;
        *(int4*)&Alds[pw][(tid + 256) * 8] = ha1;
        *(int4*)&Blds[pw][tid * 8]         = hb0;
        *(int4*)&Blds[pw][(tid + 256) * 8] = hb1;
        ha0 = na0; ha1 = na1; hb0 = nb0; hb1 = nb1;
        __syncthreads();
        p = pw; pw = (pw == 2) ? 0 : pw + 1;
    }

    const int mbase = m0 + (wave & 1) * 64, nbase = n0 + (wave >> 1) * 64;
#pragma unroll
    for (int mt = 0; mt < 4; mt++) {
        int co0 = mbase + mt * 16 + q * 4;
        float b0 = bias[co0 + 0], b1 = bias[co0 + 1];
        float b2 = bias[co0 + 2], b3 = bias[co0 + 3];
#pragma unroll
        for (int nt = 0; nt < 4; nt++) {
            int scol = nbase + nt * 16 + c;
            float v0 = (acc[mt][nt][0] + b0) * scale;
            float v1 = (acc[mt][nt][1] + b1) * scale;
            float v2 = (acc[mt][nt][2] + b2) * scale;
            float v3 = (acc[mt][nt][3] + b3) * scale;
            float* o = (float*)out;
            o[((size_t)(b * 512 + co0 + 0)) * 4096 + scol] = v0;
            o[((size_t)(b * 512 + co0 + 1)) * 4096 + scol] = v1;
            o[((size_t)(b * 512 + co0 + 2)) * 4096 + scol] = v2;
            o[((size_t)(b * 512 + co0 + 3)) * 4096 + scol] = v3;
        }
    }
    (void)mode;
}

// final projection: blockIdx.z = batch, f32 output
__global__ __launch_bounds__(256) void projp_kernel(const u16* __restrict__ Wp,
                                                    const float* __restrict__ bp,
                                                    const u16* __restrict__ attout,
                                                    float* __restrict__ out) {
    __shared__ u16 Alds[3][4096];
    __shared__ u16 Blds[3][4096];
    const int b = blockIdx.z;
    proj_core(Wp, bp, attout + (size_t)b * (4096 * 512), out, b, 2, 1.0f, Alds, Blds);
}

// ---------------------------------------------------------------------------
// 3) Flash attention (R5 structure, NO setprio) + XCD-AWARE BLOCK REMAP (R7):
//    bijective remap lin -> (xs, yz) puts all 32 s-blocks sharing one K/V
//    slice (bhd,z) on the SAME presumed XCD (lin%8), 4 slices x 512KB = 2MB
//    per 4MB L2 -> K/V L2-resident per XCD (measured: FETCH 72.7 -> 12.4MB).
//    Fixed-base softmax, T-SPLIT, V-frags hoisted to registers, reg-staged
//    K/V double-buffer, ONE barrier per iteration. grid = 1024 blocks
//    (LDS 40 KB). Blocks write UNNORMALIZED f32 O^T partials + partial
//    row-sums (merged by merge_kernel).
// ---------------------------------------------------------------------------
__global__ __launch_bounds__(256, 4) void attn_kernel(const u16* __restrict__ Qm,
                                                      const u16* __restrict__ Km,
                                                      const u16* __restrict__ Vm,
                                                      float* __restrict__ Opart,
                                                      float* __restrict__ Lpart) {
    __shared__ u16 Klds[2][4096];     // 2 x 8KB, frag order (t4,kk,qq,r)
    __shared__ u16 Vlds[2][4096];     // 2 x 8KB, frag order (t4,kk,qq,r)
    __shared__ u16 Plds[4][1024];     // per-wave 2KB frag-order P^T (one st half)
    const int tid = threadIdx.x, wave = tid >> 6, lane = tid & 63;
    const int q = lane >> 4, c = lane & 15;

    // XCD-aware remap (bijective on 1024 blocks):
    //   lin%8 = presumed XCD; slice yz = g + 8*(i>>5) so one K/V slice's 32
    //   s-blocks share an XCD. Inverse: lin = (slice*32+xs)*8 + (yz%8).
    const int lin = blockIdx.x + (blockIdx.y << 5) + (blockIdx.z << 9);
    const int g = lin & 7, i = lin >> 3;
    const int xs = i & 31, slice = i >> 5;
    const int yz = g + slice * 8;          // 0..31
    const int bhd = yz & 15, z = yz >> 4, s0 = xs * 128;

    const int tbase = z * 2048;
    const u16* Qb = Qm + (size_t)bhd * (4096 * 64);
    const u16* Kb = Km + (size_t)bhd * (4096 * 64);
    const u16* Vb = Vm + (size_t)bhd * (64 * 4096);

    bf16x8 qf[2][2];
#pragma unroll
    for (int st = 0; st < 2; st++)
#pragma unroll
        for (int kd = 0; kd < 2; kd++)
            qf[st][kd] = *(const bf16x8*)
                &Qb[(size_t)(s0 + wave * 32 + st * 16 + c) * 64 + kd * 32 + q * 8];

    const int rr = tid & 15, qq = (tid >> 4) & 3, kk = (tid >> 6) & 1;
    const int t40 = tid >> 7, t41 = t40 + 2;
    const u16* Ksrc0 = Kb + (size_t)(tbase + t40 * 16 + rr) * 64 + kk * 32 + qq * 8;
    const u16* Ksrc1 = Kb + (size_t)(tbase + t41 * 16 + rr) * 64 + kk * 32 + qq * 8;
    const u16* Vsrc0 = Vb + (size_t)(t40 * 16 + rr) * 4096 + tbase + kk * 32 + qq * 8;
    const u16* Vsrc1 = Vb + (size_t)(t41 * 16 + rr) * 4096 + tbase + kk * 32 + qq * 8;

    u16* Pwr       = &Plds[wave][(q >> 1) * 128 + (q & 1) * 4 + c * 8];
    const u16* Prd = &Plds[wave][q * 128 + c * 8];

    f32x4 oacc[4][2] = {};            // [dt][st]: O^T rows dv, cols s
    float lsum[2] = {0.f, 0.f};

    *(int4*)&Klds[0][tid * 8]         = *(const int4*)&Ksrc0[0];
    *(int4*)&Klds[0][(tid + 256) * 8] = *(const int4*)&Ksrc1[0];
    *(int4*)&Vlds[0][tid * 8]         = *(const int4*)&Vsrc0[0];
    *(int4*)&Vlds[0][(tid + 256) * 8] = *(const int4*)&Vsrc1[0];
    __syncthreads();

    for (int it = 0; it < 32; it++) {
        const int p = it & 1;
        const size_t t0n = (size_t)(((it + 1) & 31) * 64);  // next tile (wraps)

        int4 kst0 = *(const int4*)&Ksrc0[t0n * 64];
        int4 kst1 = *(const int4*)&Ksrc1[t0n * 64];
        int4 vst0 = *(const int4*)&Vsrc0[t0n];
        int4 vst1 = *(const int4*)&Vsrc1[t0n];

        f32x4 sacc[4][2] = {};
#pragma unroll
        for (int kd = 0; kd < 2; kd++) {
            bf16x8 ka[4];
#pragma unroll
            for (int tt = 0; tt < 4; tt++)
                ka[tt] = *(const bf16x8*)&Klds[p][(((tt * 2 + kd) * 4 + q) * 16 + c) * 8];
#pragma unroll
            for (int tt = 0; tt < 4; tt++)
#pragma unroll
                for (int st = 0; st < 2; st++)
                    sacc[tt][st] = mfma16(ka[tt], qf[st][kd], sacc[tt][st]);
        }

        bf16x8 va[2][4];
#pragma unroll
        for (int kt = 0; kt < 2; kt++)
#pragma unroll
            for (int dt = 0; dt < 4; dt++)
                va[kt][dt] = *(const bf16x8*)&Vlds[p][(((dt * 2 + kt) * 4 + q) * 16 + c) * 8];

#pragma unroll
        for (int st = 0; st < 2; st++) {
#pragma unroll
            for (int tt = 0; tt < 4; tt++) {
                float p0 = fexp2(sacc[tt][st][0]);
                float p1 = fexp2(sacc[tt][st][1]);
                float p2 = fexp2(sacc[tt][st][2]);
                float p3 = fexp2(sacc[tt][st][3]);
                lsum[st] += (p0 + p1) + (p2 + p3);
                uint2 pv; pv.x = pack2(p0, p1); pv.y = pack2(p2, p3);
                *(uint2*)&Pwr[tt * 256] = pv;
            }
#pragma unroll
            for (int kt = 0; kt < 2; kt++) {
                bf16x8 pb = *(const bf16x8*)&Prd[kt * 512];
#pragma unroll
                for (int dt = 0; dt < 4; dt++)
                    oacc[dt][st] = mfma16(va[kt][dt], pb, oacc[dt][st]);
            }
        }

        *(int4*)&Klds[1 - p][tid * 8]         = kst0;
        *(int4*)&Klds[1 - p][(tid + 256) * 8] = kst1;
        *(int4*)&Vlds[1 - p][tid * 8]         = vst0;
        *(int4*)&Vlds[1 - p][(tid + 256) * 8] = vst1;
        __syncthreads();
    }

#pragma unroll
    for (int st = 0; st < 2; st++) {
        float l = lsum[st];
        l += __shfl_xor(l, 16, 64);
        l += __shfl_xor(l, 32, 64);
        const int s = s0 + wave * 32 + st * 16 + c;
        const size_t rowbase = ((size_t)(z * 16 + bhd) * 4096 + s) * 64;
#pragma unroll
        for (int dt = 0; dt < 4; dt++) {
            float4 ov;
            ov.x = oacc[dt][st][0];
            ov.y = oacc[dt][st][1];
            ov.z = oacc[dt][st][2];
            ov.w = oacc[dt][st][3];
            *(float4*)&Opart[rowbase + dt * 16 + q * 4] = ov;
        }
        if (lane < 16)
            Lpart[(size_t)z * 65536 + bhd * 4096 + s0 + wave * 32 + st * 16 + lane] = l;
    }
}

// ---------------------------------------------------------------------------
// 3b) merge: attout[b][s][hd*64+dv] = (O0+O1) / (l0+l1), f32 -> bf16.
// ---------------------------------------------------------------------------
__global__ __launch_bounds__(256) void merge_kernel(const float* __restrict__ Opart,
                                                    const float* __restrict__ Lpart,
                                                    u16* __restrict__ attout) {
    const int i = blockIdx.x * 256 + threadIdx.x;
    const int flat = i * 4;                  // f32 index within [16][4096][64]
    const int row = flat >> 6, dv = flat & 63;
    const int bhd = row >> 12, s = row & 4095;
    const float l = Lpart[row] + Lpart[65536 + row];
    const float rl = 1.0f / l;
    const float4 a  = *(const float4*)&Opart[flat];
    const float4 b4 = *(const float4*)&Opart[4194304 + flat];
    uint2 pv;
    pv.x = pack2((a.x + b4.x) * rl, (a.y + b4.y) * rl);
    pv.y = pack2((a.z + b4.z) * rl, (a.w + b4.w) * rl);
    const int b = bhd >> 3, hd = bhd & 7;
    *(uint2*)&attout[((size_t)(b * 4096 + s)) * 512 + hd * 64 + dv] = pv;
}

// ---------------------------------------------------------------------------
extern "C" void kernel_launch(void* const* d_in, const int* in_sizes, int n_in,
                              void* d_out, int out_size, void* d_ws, size_t ws_size,
                              hipStream_t stream) {
    (void)in_sizes; (void)n_in; (void)out_size; (void)ws_size;
    const float* x  = (const float*)d_in[0];
    const float* Wq = (const float*)d_in[1];
    const float* bq = (const float*)d_in[2];
    const float* Wk = (const float*)d_in[3];
    const float* bk = (const float*)d_in[4];
    const float* Wv = (const float*)d_in[5];
    const float* bv = (const float*)d_in[6];
    const float* Wp = (const float*)d_in[7];
    const float* bp = (const float*)d_in[8];
    float* out = (float*)d_out;

    const size_t NTOK = (size_t)4 * 1024 * 1024;  // 2*4096*512 elements
    u16* tok = (u16*)d_ws;        // [2][4096][512] bf16; reused as attout later
    u16* Qb  = tok + NTOK;        // [16][4096][64]  (pre-scaled by log2e/8)
    u16* Kb  = Qb + NTOK;         // [16][4096][64]
    u16* Vb  = Kb + NTOK;         // [16][64][4096]
    u16* Wbf = Vb + NTOK;         // [4][512][512] bf16 (q,k,v,p)
    u16* attout = tok;            // alias: tok dead after V projection
    float* Opart = (float*)(Wbf + 4 * 262144);  // [2][16][4096][64] f32 (33.5MB)
    float* Lpart = Opart + (size_t)2 * 4194304; // [2][16][4096] f32 (512KB)

    prep_kernel<<<dim3(2048), 256, 0, stream>>>(x, tok, Wq, Wk, Wv, Wp, Wbf);
    qkv3_kernel<<<dim3(32, 8, 2), 256, 0, stream>>>(Wbf, bq, bk, bv, tok, Qb, Kb, Vb);
    attn_kernel<<<dim3(32, 16, 2), 256, 0, stream>>>(Qb, Kb, Vb, Opart, Lpart);
    merge_kernel<<<dim3(4096), 256, 0, stream>>>(Opart, Lpart, attout);
    projp_kernel<<<dim3(32, 4, 2), 256, 0, stream>>>(Wbf + 3 * 262144, bp, attout, out);
}